// Round 2
// baseline (188663.037 us; speedup 1.0000x reference)
//
#include <hip/hip_runtime.h>

#define RES      8192
#define IN_DIM   64
#define DYN      1000
#define TOT      2000

#define BLOCKS   256          // exactly 1 block per CU -> co-residency by construction
#define TPB      1024
#define WPB      (TPB / 64)   // 16 waves per block
#define NWAVES   (BLOCKS * WPB)  // 4096 waves, 2 W_h rows each

// Output layout (floats):
//   prediction          [     0 ..  63999]   (1000 x 64)
//   target              [ 64000 .. 127999]   copy of input[1000:2000]
//   prediction_augment  [128000 .. 255999]   (2000 x 64)
//   target_augment      [256000 .. 383999]   copy of input
//
// ws layout (floats): h0[8192], h1[8192], outbuf[64], barrier{count,gen}

__global__ void copy_targets(const float* __restrict__ input, float* __restrict__ out) {
    int i = blockIdx.x * blockDim.x + threadIdx.x;
    if (i < 64000)  out[64000 + i]  = input[64000 + i];   // target
    if (i < 128000) out[256000 + i] = input[i];           // target_augment
}

// Sense-reversing grid barrier. All BLOCKS blocks are co-resident (1/CU).
// Release fence before arrival publishes this block's global stores;
// acquire fence after release ensures we see everyone else's.
__device__ __forceinline__ void grid_barrier(unsigned* count, unsigned* gen) {
    __syncthreads();
    if (threadIdx.x == 0) {
        __threadfence();  // release: publish h/outbuf stores device-wide
        unsigned g = __hip_atomic_load(gen, __ATOMIC_RELAXED, __HIP_MEMORY_SCOPE_AGENT);
        unsigned a = __hip_atomic_fetch_add(count, 1u, __ATOMIC_ACQ_REL, __HIP_MEMORY_SCOPE_AGENT);
        if (a == BLOCKS - 1) {
            // last arriver: reset count BEFORE bumping gen (waiters can't touch
            // count again until they observe the gen bump)
            __hip_atomic_store(count, 0u, __ATOMIC_RELAXED, __HIP_MEMORY_SCOPE_AGENT);
            __hip_atomic_fetch_add(gen, 1u, __ATOMIC_RELEASE, __HIP_MEMORY_SCOPE_AGENT);
        } else {
            while (__hip_atomic_load(gen, __ATOMIC_RELAXED, __HIP_MEMORY_SCOPE_AGENT) == g)
                __builtin_amdgcn_s_sleep(2);
        }
        __threadfence();  // acquire: invalidate stale cached lines
    }
    __syncthreads();
}

__global__ __launch_bounds__(TPB, 4) void esn_kernel(
    const float* __restrict__ input,   // 2000 x 64
    const float* __restrict__ W_in,    // 8192 x 64
    const float* __restrict__ W_h,     // 8192 x 8192
    const float* __restrict__ W_out,   // 64 x 8192
    float* __restrict__ out,
    float* __restrict__ ws)
{
    __shared__ __align__(16) float h_lds[RES];

    float* hbuf0  = ws;
    float* hbuf1  = ws + RES;
    float* outbuf = ws + 2 * RES;
    unsigned* bar_count = (unsigned*)(ws + 2 * RES + 64);
    unsigned* bar_gen   = bar_count + 1;

    float* pred    = out;            // prediction
    float* aug_out = out + 128000;   // prediction_augment

    const int tid  = threadIdx.x;
    const int lane = tid & 63;
    const int wid  = tid >> 6;                    // wave id in block [0,16)
    const int gw   = blockIdx.x * WPB + wid;      // global wave id [0,4096)

    for (int t = 0; t < TOT; ++t) {
        const float* hcur = (t & 1) ? hbuf1 : hbuf0;
        float*       hnxt = (t & 1) ? hbuf0 : hbuf1;

        // ---- stage h into LDS (32 KB per block) ----
        {
            const float4* src = (const float4*)hcur;
            float4*       dst = (float4*)h_lds;
            #pragma unroll
            for (int i = 0; i < RES / 4 / TPB; ++i)
                dst[tid + i * TPB] = src[tid + i * TPB];
        }
        __syncthreads();

        // ---- out_t = W_out @ aug(h_t): row j handled by wave 0 of block j ----
        // (spread over 64 different CUs so no CU becomes a traffic straggler)
        if (wid == 0 && blockIdx.x < 64 && t >= 1) {
            const int j = blockIdx.x;
            const float* wrow = W_out + (size_t)j * RES;
            float acc = 0.f;
            #pragma unroll 4
            for (int i = 0; i < RES / 256; ++i) {
                const int k = (lane << 2) + (i << 8);
                float4 w = *(const float4*)(wrow + k);
                float4 h = *(const float4*)(h_lds + k);
                // aug: even index -> h*h, odd -> h; k is a multiple of 4
                acc += w.x * h.x * h.x + w.y * h.y + w.z * h.z * h.z + w.w * h.w;
            }
            #pragma unroll
            for (int off = 32; off; off >>= 1) acc += __shfl_xor(acc, off, 64);
            if (lane == 0) {
                if (t <= DYN)  aug_out[(size_t)(t - 1) * 64 + j] = acc;  // warm_out[t-1]
                if (t >= DYN) {
                    pred[(size_t)(t - DYN) * 64 + j] = acc;              // prediction
                    aug_out[(size_t)t * 64 + j]      = acc;              // aug[1000+s]
                    outbuf[j]                        = acc;              // fed back
                }
            }
        }

        // In prediction phases the h-update consumes out_t -> publish it first.
        if (t >= DYN) grid_barrier(bar_count, bar_gen);

        const float* xv = (t < DYN) ? (input + (size_t)t * IN_DIM) : outbuf;
        const float x_l = xv[lane];

        // ---- h_{t+1} = tanh(W_in @ x_t + W_h @ h_t), 2 rows per wave ----
        #pragma unroll
        for (int rr = 0; rr < RES / NWAVES; ++rr) {
            const int r = gw + rr * NWAVES;
            const float* wrow = W_h + (size_t)r * RES;
            float a0 = 0.f, a1 = 0.f, a2 = 0.f, a3 = 0.f;
            #pragma unroll 4
            for (int i = 0; i < RES / 256; ++i) {
                const int k = (lane << 2) + (i << 8);
                float4 w = *(const float4*)(wrow + k);
                float4 h = *(const float4*)(h_lds + k);
                a0 += w.x * h.x; a1 += w.y * h.y;
                a2 += w.z * h.z; a3 += w.w * h.w;
            }
            float acc = (a0 + a2) + (a1 + a3);
            acc += W_in[(size_t)r * IN_DIM + lane] * x_l;
            #pragma unroll
            for (int off = 32; off; off >>= 1) acc += __shfl_xor(acc, off, 64);
            if (lane == 0) hnxt[r] = tanhf(acc);
        }

        grid_barrier(bar_count, bar_gen);
    }
}

extern "C" void kernel_launch(void* const* d_in, const int* in_sizes, int n_in,
                              void* d_out, int out_size, void* d_ws, size_t ws_size,
                              hipStream_t stream) {
    const float* input = (const float*)d_in[0];
    const float* W_in  = (const float*)d_in[1];
    const float* W_h   = (const float*)d_in[2];
    const float* W_out = (const float*)d_in[3];
    float* out = (float*)d_out;
    float* ws  = (float*)d_ws;

    // h buffers + outbuf + barrier vars must start at zero (ws is poisoned 0xAA)
    hipMemsetAsync(d_ws, 0, (2 * RES + 64 + 16) * sizeof(float), stream);

    copy_targets<<<dim3((128000 + 255) / 256), dim3(256), 0, stream>>>(input, out);

    esn_kernel<<<dim3(BLOCKS), dim3(TPB), 0, stream>>>(input, W_in, W_h, W_out, out, ws);
}